// Round 1
// 2094.734 us; speedup vs baseline: 1.1301x; 1.1301x over previous
//
#include <hip/hip_runtime.h>
#include <hip/hip_bf16.h>

#define NN 20000
#define EE 640000

// WS budget: harness ws_size is finite (~16 MB observed safe in R1).
// Total here = 3,932,769 floats = 15.73 MB. zh/zl (bf16 split of z, 5.12 MB)
// alias h (dead after spmm#1). Exceeding ws_size corrupts neighboring
// allocations -> post-timing divergence.

typedef float f32x4 __attribute__((ext_vector_type(4)));
typedef short short8 __attribute__((ext_vector_type(8)));   // 8 bf16 = 4 VGPRs

__device__ __forceinline__ float sigf(float x) {
    return __builtin_amdgcn_rcpf(1.0f + __builtin_amdgcn_exp2f(x * -1.442695041f));
}

__global__ void fill_zero_i32(int* __restrict__ p, int n) {
    int i = blockIdx.x * 256 + threadIdx.x;
    if (i < n) p[i] = 0;
}

__global__ void count_rows(const int* __restrict__ rows, int* __restrict__ cnt, int e) {
    int i = blockIdx.x * 256 + threadIdx.x;
    if (i < e) atomicAdd(&cnt[rows[i]], 1);
}

__global__ __launch_bounds__(1024) void scan_counts(const int* __restrict__ cnt,
                                                    int* __restrict__ off,
                                                    int* __restrict__ cursor, int n) {
    __shared__ int part[1024];
    int tid = threadIdx.x;
    const int per = (n + 1023) / 1024;
    int base = tid * per;
    int s = 0;
    for (int i = 0; i < per; ++i) {
        int idx = base + i;
        if (idx < n) s += cnt[idx];
    }
    part[tid] = s;
    __syncthreads();
    for (int d = 1; d < 1024; d <<= 1) {
        int v = (tid >= d) ? part[tid - d] : 0;
        __syncthreads();
        part[tid] += v;
        __syncthreads();
    }
    int run = (tid == 0) ? 0 : part[tid - 1];
    for (int i = 0; i < per; ++i) {
        int idx = base + i;
        if (idx < n) {
            off[idx] = run;
            cursor[idx] = run;
            run += cnt[idx];
        }
    }
    if (tid == 1023) off[n] = part[1023];
}

__global__ void scatter_edges(const int* __restrict__ rows, const int* __restrict__ cols,
                              const float* __restrict__ vals, int* __restrict__ cursor,
                              int* __restrict__ col_s, float* __restrict__ val_s, int e) {
    int i = blockIdx.x * 256 + threadIdx.x;
    if (i < e) {
        int p = atomicAdd(&cursor[rows[i]], 1);
        col_s[p] = cols[i];
        val_s[p] = vals[i];
    }
}

// C[M,Nc] = A[M,K] @ B[K,Nc]; 64x64 tile, 256 threads, 4x4 per thread.
__global__ __launch_bounds__(256) void sgemm64(const float* __restrict__ A,
                                               const float* __restrict__ B,
                                               float* __restrict__ C, int M, int K, int Nc) {
    __shared__ float As[16][65];
    __shared__ float Bs[16][65];
    int tid = threadIdx.x;
    int tm = (tid >> 4) << 2;
    int tn = (tid & 15) << 2;
    int m0 = blockIdx.y * 64;
    int n0 = blockIdx.x * 64;
    float acc[4][4] = {};
    for (int k0 = 0; k0 < K; k0 += 16) {
        for (int i = tid; i < 64 * 16; i += 256) {
            int r = i >> 4, c = i & 15;
            int gr = m0 + r;
            As[c][r] = (gr < M) ? A[(long)gr * K + k0 + c] : 0.0f;
        }
        for (int i = tid; i < 16 * 64; i += 256) {
            int kk = i >> 6, c = i & 63;
            Bs[kk][c] = B[(long)(k0 + kk) * Nc + n0 + c];
        }
        __syncthreads();
        #pragma unroll
        for (int kk = 0; kk < 16; ++kk) {
            float a[4], b[4];
            #pragma unroll
            for (int x = 0; x < 4; ++x) a[x] = As[kk][tm + x];
            #pragma unroll
            for (int y = 0; y < 4; ++y) b[y] = Bs[kk][tn + y];
            #pragma unroll
            for (int x = 0; x < 4; ++x)
                #pragma unroll
                for (int y = 0; y < 4; ++y)
                    acc[x][y] = fmaf(a[x], b[y], acc[x][y]);
        }
        __syncthreads();
    }
    for (int x = 0; x < 4; ++x) {
        int gr = m0 + tm + x;
        if (gr < M) {
            #pragma unroll
            for (int y = 0; y < 4; ++y) C[(long)gr * Nc + n0 + tn + y] = acc[x][y];
        }
    }
}

// Y[row,:] = sum_e val[e] * X[col[e],:]; optionally emits split-bf16 copy
// (ZH = bf16(acc), ZL = bf16(acc - ZH)) for the MFMA decoder.
__global__ __launch_bounds__(256) void spmm_csr64(const int* __restrict__ off,
                                                  const int* __restrict__ col_s,
                                                  const float* __restrict__ val_s,
                                                  const float* __restrict__ X,
                                                  float* __restrict__ Y,
                                                  __hip_bfloat16* __restrict__ ZH,
                                                  __hip_bfloat16* __restrict__ ZL, int n) {
    int row = blockIdx.x * 4 + (threadIdx.x >> 6);
    if (row >= n) return;
    int lane = threadIdx.x & 63;
    int e0 = off[row], e1 = off[row + 1];
    float acc = 0.0f;
    for (int e = e0; e < e1; ++e) {
        acc = fmaf(val_s[e], X[(long)col_s[e] * 64 + lane], acc);
    }
    Y[(long)row * 64 + lane] = acc;
    if (ZH) {
        __hip_bfloat16 hi = __float2bfloat16(acc);
        __hip_bfloat16 lo = __float2bfloat16(acc - __bfloat162float(hi));
        ZH[(long)row * 64 + lane] = hi;
        ZL[(long)row * 64 + lane] = lo;
    }
}

// A[i,j] = sigmoid(dot(Z[i],Z[j])) via bf16 MFMA with split representation:
// dot = hi.hi + hi.lo + lo.hi  (error ~2^-16 relative of term magnitude,
// same order as fp32 reorder noise; lo.lo term negligible).
// Block = 128x128 output, 4 waves (2x2), each wave 64x64 = 4x4 MFMA tiles.
// K=64 = 2 chunks of 32. Both operands are rows of Z ([N,64] row-major ==
// B^T layout) -> A-frag and B-frag load identically: lane l reads 8
// contiguous bf16 at row (base + l&15), k = kc*32 + (l>>4)*8. No LDS.
// C/D layout (m89): col = lane&15, row = (lane>>4)*4 + reg.
__global__ __launch_bounds__(256, 2) void decoder_mfma(const __hip_bfloat16* __restrict__ ZH,
                                                       const __hip_bfloat16* __restrict__ ZL,
                                                       float* __restrict__ A, int n) {
    const short8* Zh8 = (const short8*)ZH;   // row stride = 8 short8 units (64 bf16)
    const short8* Zl8 = (const short8*)ZL;
    int tid = threadIdx.x;
    int lane = tid & 63;
    int wid = tid >> 6;
    int wrow = wid >> 1, wcol = wid & 1;
    int i0 = (blockIdx.y << 7) + (wrow << 6);
    int j0 = (blockIdx.x << 7) + (wcol << 6);
    int r16 = lane & 15;
    int kg = lane >> 4;                      // 0..3 : k-group of 8

    f32x4 acc[4][4] = {};

    #pragma unroll
    for (int kc = 0; kc < 2; ++kc) {
        short8 ah[4], al[4], bh[4], bl[4];
        #pragma unroll
        for (int t = 0; t < 4; ++t) {
            int ra = i0 + t * 16 + r16; ra = (ra < n) ? ra : (n - 1);   // clamp OOB loads
            int rb = j0 + t * 16 + r16; rb = (rb < n) ? rb : (n - 1);   // (stores guarded)
            long oa = (long)ra * 8 + kc * 4 + kg;
            long ob = (long)rb * 8 + kc * 4 + kg;
            ah[t] = Zh8[oa];
            al[t] = Zl8[oa];
            bh[t] = Zh8[ob];
            bl[t] = Zl8[ob];
        }
        #pragma unroll
        for (int ti = 0; ti < 4; ++ti)
            #pragma unroll
            for (int tj = 0; tj < 4; ++tj) {
                acc[ti][tj] = __builtin_amdgcn_mfma_f32_16x16x32_bf16(ah[ti], bh[tj], acc[ti][tj], 0, 0, 0);
                acc[ti][tj] = __builtin_amdgcn_mfma_f32_16x16x32_bf16(ah[ti], bl[tj], acc[ti][tj], 0, 0, 0);
                acc[ti][tj] = __builtin_amdgcn_mfma_f32_16x16x32_bf16(al[ti], bh[tj], acc[ti][tj], 0, 0, 0);
            }
    }

    #pragma unroll
    for (int ti = 0; ti < 4; ++ti) {
        int gib = i0 + ti * 16 + (kg << 2);
        #pragma unroll
        for (int q = 0; q < 4; ++q) {
            int gi = gib + q;
            if (gi < n) {
                long rowb = (long)gi * n;
                #pragma unroll
                for (int tj = 0; tj < 4; ++tj) {
                    int gj = j0 + tj * 16 + r16;
                    if (gj < n) A[rowb + gj] = sigf(acc[ti][tj][q]);
                }
            }
        }
    }
}

extern "C" void kernel_launch(void* const* d_in, const int* in_sizes, int n_in,
                              void* d_out, int out_size, void* d_ws, size_t ws_size,
                              hipStream_t stream) {
    const float* feat     = (const float*)d_in[0];
    const int*   adj_rows = (const int*)d_in[1];
    const int*   adj_cols = (const int*)d_in[2];
    const float* adj_vals = (const float*)d_in[3];
    const float* W1       = (const float*)d_in[4];
    const float* W2       = (const float*)d_in[5];

    float* out  = (float*)d_out;
    float* z    = out;                           // [20000,64]
    float* Arec = out + (long)NN * 64;           // [20000,20000]

    // Compact ws layout (15.73 MB total; zh/zl alias h which is dead after spmm#1)
    float* W12   = (float*)d_ws;                 // 512*64
    float* h     = W12 + 512 * 64;               // [N,64]  (reused as zh/zl bf16)
    float* hz    = h + (long)NN * 64;            // [N,64]
    float* val_s = hz + (long)NN * 64;           // [E]
    int*   col_s = (int*)(val_s + EE);           // [E]
    int*   cnt   = col_s + EE;                   // [N]
    int*   off   = cnt + NN;                     // [N+1]
    int*   cursor= off + NN + 1;                 // [N]
    __hip_bfloat16* zh = (__hip_bfloat16*)h;     // [N,64] bf16 (2.56 MB)
    __hip_bfloat16* zl = zh + (long)NN * 64;     // [N,64] bf16 (2.56 MB) — ends at hz

    fill_zero_i32<<<(NN + 255) / 256, 256, 0, stream>>>(cnt, NN);
    count_rows<<<(EE + 255) / 256, 256, 0, stream>>>(adj_rows, cnt, EE);
    scan_counts<<<1, 1024, 0, stream>>>(cnt, off, cursor, NN);
    scatter_edges<<<(EE + 255) / 256, 256, 0, stream>>>(adj_rows, adj_cols, adj_vals,
                                                        cursor, col_s, val_s, EE);

    // W12 = W1@W2 ; h = feat@W12  (associativity: (A(A(feat@W1)))@W2 == A(A(feat@(W1@W2))))
    sgemm64<<<dim3(1, (512 + 63) / 64), 256, 0, stream>>>(W1, W2, W12, 512, 256, 64);
    sgemm64<<<dim3(1, (NN + 63) / 64), 256, 0, stream>>>(feat, W12, h, NN, 512, 64);

    // hz = A@h ; then z = A@hz (spmm#2 also emits split-bf16 z into h's storage)
    spmm_csr64<<<(NN + 3) / 4, 256, 0, stream>>>(off, col_s, val_s, h, hz,
                                                 nullptr, nullptr, NN);
    spmm_csr64<<<(NN + 3) / 4, 256, 0, stream>>>(off, col_s, val_s, hz, z, zh, zl, NN);

    decoder_mfma<<<dim3((NN + 127) / 128, (NN + 127) / 128), 256, 0, stream>>>(zh, zl, Arec, NN);
}